// Round 1
// 418.769 us; speedup vs baseline: 1.0061x; 1.0061x over previous
//
#include <hip/hip_runtime.h>

// GetCostVolume: out[0, 0:C,  d,h,w] = x[c,h,w]   (broadcast over d)
//                out[0, C:2C, d,h,w] = bilinear_zeros(y[c], ix(d,h,w), iy(h))
// B=1, C=32, H=128, W=256, D=48.
//
// v2: full-W wave rows. lane = w-quad (64 lanes x 4w = 256 = W), so every v4f
// store writes a 1-KB contiguous (c,d,h) row (was 256-B chunks -> poor HBM
// page locality). Gathers stay c-vectorized (v4f along c) since that lives in
// per-thread registers, independent of lane mapping. Params (wx, j) computed
// in registers per lane (no s_wx/s_xj LDS). Grid = (h, c-half, d-half) = 512
// blocks x 512 threads, LDS 51.8 KB -> 2 blocks/CU = 16 waves/CU.

typedef float v4f __attribute__((ext_vector_type(4)));

namespace {
constexpr int C = 32, D = 48, H = 128, W = 256;
constexpr int HW  = H * W;        // 32768
constexpr int DHW = D * HW;       // 1,572,864
constexpr int SPAN = 324;         // staged x span: [-66, 257]
constexpr int XLO  = -66;
constexpr int CP   = 20;          // 16 channels + 4 pad (v4f-aligned; 5 odd -> bank spread)
}

__global__ __launch_bounds__(512, 4) void cost_volume_kernel(
    const float* __restrict__ x, const float* __restrict__ y,
    const float* __restrict__ disp, float* __restrict__ out)
{
    __shared__ __align__(16) float ys[2 * SPAN * CP];   // [(row*SPAN+j)*CP + c] = 51,840 B

    const int t     = threadIdx.x;
    const int bx    = blockIdx.x;
    const int h     = bx >> 2;          // 128 h rows
    const int ch    = (bx >> 1) & 1;    // 16-channel half
    const int dh    = bx & 1;           // 24-disparity half
    const int cb    = ch * 16;
    const int dbase = dh * 24;

    // ---- y-row interpolation params (block-uniform) ----
    const float gy  = (float)h / 63.5f - 1.0f;                // (H-1)/2
    const float iy  = ((gy + 1.0f) * 128.0f - 1.0f) * 0.5f;
    const float y0f = floorf(iy);
    const float wy  = iy - y0f;
    const int   y0i = (int)y0f;

    // ---- stage 2 y-rows x 16 c x SPAN j, zeros for OOB (replaces masks) ----
    {
        const int combo = t >> 4;          // 0..31 : row*16 + cc
        const int row = combo >> 4;
        const int cc  = combo & 15;
        const int yr  = y0i + row;
        const bool vr = (yr >= 0) && (yr < H);
        const float* ysrc = y + (cb + cc) * HW + yr * W;
        for (int j = (t & 15); j < SPAN; j += 16) {
            const int xg = XLO + j;
            float v = 0.0f;
            if (vr && xg >= 0 && xg < W) v = ysrc[xg];
            ys[(row * SPAN + j) * CP + cc] = v;
        }
    }

    const int wave = t >> 6;               // 8 waves
    const int lane = t & 63;
    const int w0   = 4 * lane;             // lane covers w-quad -> full W per wave

    // left-half x rows: load early (overlaps staging latency), store at the end
    v4f xv0 = *(const v4f*)(x + (cb + wave * 2 + 0) * HW + h * W + w0);
    v4f xv1 = *(const v4f*)(x + (cb + wave * 2 + 1) * HW + h * W + w0);

    __syncthreads();

    // ---- warp half: each wave owns 3 d values, writes 1-KB rows per (c,d) ----
    const float omy = 1.0f - wy;
    float* const outw = out + (C + cb) * DHW + h * W + w0;

    for (int dd = 0; dd < 3; ++dd) {
        const int d = dbase + wave * 3 + dd;
        const v4f dv = *(const v4f*)(disp + d * HW + h * W + w0);
        float wgt[4][4]; int jj[4];
#pragma unroll
        for (int k = 0; k < 4; ++k) {
            const float cur = (float)(w0 + k) - dv[k];
            const float gx  = cur / 127.5f - 1.0f;                // (W-1)/2
            const float ix  = ((gx + 1.0f) * 256.0f - 1.0f) * 0.5f;
            const float x0f = floorf(ix);
            const float wx  = ix - x0f;
            jj[k] = min(max((int)x0f - XLO, 0), SPAN - 2);        // safety clamp
            const float omx = 1.0f - wx;
            wgt[k][0] = omx * omy; wgt[k][1] = wx * omy;
            wgt[k][2] = omx * wy;  wgt[k][3] = wx * wy;
        }
#pragma unroll
        for (int cq = 0; cq < 4; ++cq) {
            const int c0 = cq * 4;
            float res[4][4];
#pragma unroll
            for (int k = 0; k < 4; ++k) {
                const float* p0 = ys + jj[k] * CP + c0;          // row 0, x0
                const float* p1 = p0 + SPAN * CP;                // row 1
                const v4f v00 = *(const v4f*)p0;
                const v4f v01 = *(const v4f*)(p0 + CP);          // x0+1
                const v4f v10 = *(const v4f*)p1;
                const v4f v11 = *(const v4f*)(p1 + CP);
#pragma unroll
                for (int cc = 0; cc < 4; ++cc)
                    res[cc][k] = fmaf(v11[cc], wgt[k][3], fmaf(v10[cc], wgt[k][2],
                                  fmaf(v01[cc], wgt[k][1], v00[cc] * wgt[k][0])));
            }
#pragma unroll
            for (int cc = 0; cc < 4; ++cc) {
                const v4f r = { res[cc][0], res[cc][1], res[cc][2], res[cc][3] };
                __builtin_nontemporal_store(r, (v4f*)(outw + (c0 + cc) * DHW + d * HW));
            }
        }
    }

    // ---- left half: broadcast x rows over this block's 24 d (1-KB rows) ----
    {
        float* op0 = out + (cb + wave * 2 + 0) * DHW + dbase * HW + h * W + w0;
        float* op1 = out + (cb + wave * 2 + 1) * DHW + dbase * HW + h * W + w0;
        for (int d = 0; d < 24; ++d) {
            __builtin_nontemporal_store(xv0, (v4f*)(op0 + d * HW));
            __builtin_nontemporal_store(xv1, (v4f*)(op1 + d * HW));
        }
    }
}

extern "C" void kernel_launch(void* const* d_in, const int* in_sizes, int n_in,
                              void* d_out, int out_size, void* d_ws, size_t ws_size,
                              hipStream_t stream) {
    const float* x    = (const float*)d_in[0];
    const float* y    = (const float*)d_in[1];
    const float* disp = (const float*)d_in[2];
    float* out = (float*)d_out;

    // (h=128) x (c-half=2) x (d-half=2) = 512 blocks, 512 threads, 51.8 KB LDS
    // -> 2 blocks/CU, 16 waves/CU
    cost_volume_kernel<<<dim3(512), dim3(512), 0, stream>>>(x, y, disp, out);
}

// Round 2
// 415.568 us; speedup vs baseline: 1.0138x; 1.0077x over previous
//
#include <hip/hip_runtime.h>

// GetCostVolume: out[0, 0:C,  d,h,w] = x[c,h,w]   (broadcast over d)
//                out[0, C:2C, d,h,w] = bilinear_zeros(y[c], ix(d,h,w), iy(h))
// B=1, C=32, H=128, W=256, D=48.
//
// v3: identical to v2 EXCEPT all output stores are plain (write-back via L2)
// instead of __builtin_nontemporal_store. A/B isolates the nt flag: both v1
// (256-B chunks) and v2 (1-KB rows) hit an identical, layout-independent
// 2.45 TB/s write ceiling; the harness fill on the same buffer hits 6.3 TB/s
// with plain stores. Theory: gfx950 nt stores bypass L2 write-combining and
// cap the HBM write stream.

typedef float v4f __attribute__((ext_vector_type(4)));

namespace {
constexpr int C = 32, D = 48, H = 128, W = 256;
constexpr int HW  = H * W;        // 32768
constexpr int DHW = D * HW;       // 1,572,864
constexpr int SPAN = 324;         // staged x span: [-66, 257]
constexpr int XLO  = -66;
constexpr int CP   = 20;          // 16 channels + 4 pad (v4f-aligned; bank spread)
}

__global__ __launch_bounds__(512, 4) void cost_volume_kernel(
    const float* __restrict__ x, const float* __restrict__ y,
    const float* __restrict__ disp, float* __restrict__ out)
{
    __shared__ __align__(16) float ys[2 * SPAN * CP];   // [(row*SPAN+j)*CP + c] = 51,840 B

    const int t     = threadIdx.x;
    const int bx    = blockIdx.x;
    const int h     = bx >> 2;          // 128 h rows
    const int ch    = (bx >> 1) & 1;    // 16-channel half
    const int dh    = bx & 1;           // 24-disparity half
    const int cb    = ch * 16;
    const int dbase = dh * 24;

    // ---- y-row interpolation params (block-uniform) ----
    const float gy  = (float)h / 63.5f - 1.0f;                // (H-1)/2
    const float iy  = ((gy + 1.0f) * 128.0f - 1.0f) * 0.5f;
    const float y0f = floorf(iy);
    const float wy  = iy - y0f;
    const int   y0i = (int)y0f;

    // ---- stage 2 y-rows x 16 c x SPAN j, zeros for OOB (replaces masks) ----
    {
        const int combo = t >> 4;          // 0..31 : row*16 + cc
        const int row = combo >> 4;
        const int cc  = combo & 15;
        const int yr  = y0i + row;
        const bool vr = (yr >= 0) && (yr < H);
        const float* ysrc = y + (cb + cc) * HW + yr * W;
        for (int j = (t & 15); j < SPAN; j += 16) {
            const int xg = XLO + j;
            float v = 0.0f;
            if (vr && xg >= 0 && xg < W) v = ysrc[xg];
            ys[(row * SPAN + j) * CP + cc] = v;
        }
    }

    const int wave = t >> 6;               // 8 waves
    const int lane = t & 63;
    const int w0   = 4 * lane;             // lane covers w-quad -> full W per wave

    // left-half x rows: load early (overlaps staging latency), store at the end
    v4f xv0 = *(const v4f*)(x + (cb + wave * 2 + 0) * HW + h * W + w0);
    v4f xv1 = *(const v4f*)(x + (cb + wave * 2 + 1) * HW + h * W + w0);

    __syncthreads();

    // ---- warp half: each wave owns 3 d values, writes 1-KB rows per (c,d) ----
    const float omy = 1.0f - wy;
    float* const outw = out + (C + cb) * DHW + h * W + w0;

    for (int dd = 0; dd < 3; ++dd) {
        const int d = dbase + wave * 3 + dd;
        const v4f dv = *(const v4f*)(disp + d * HW + h * W + w0);
        float wgt[4][4]; int jj[4];
#pragma unroll
        for (int k = 0; k < 4; ++k) {
            const float cur = (float)(w0 + k) - dv[k];
            const float gx  = cur / 127.5f - 1.0f;                // (W-1)/2
            const float ix  = ((gx + 1.0f) * 256.0f - 1.0f) * 0.5f;
            const float x0f = floorf(ix);
            const float wx  = ix - x0f;
            jj[k] = min(max((int)x0f - XLO, 0), SPAN - 2);        // safety clamp
            const float omx = 1.0f - wx;
            wgt[k][0] = omx * omy; wgt[k][1] = wx * omy;
            wgt[k][2] = omx * wy;  wgt[k][3] = wx * wy;
        }
#pragma unroll
        for (int cq = 0; cq < 4; ++cq) {
            const int c0 = cq * 4;
            float res[4][4];
#pragma unroll
            for (int k = 0; k < 4; ++k) {
                const float* p0 = ys + jj[k] * CP + c0;          // row 0, x0
                const float* p1 = p0 + SPAN * CP;                // row 1
                const v4f v00 = *(const v4f*)p0;
                const v4f v01 = *(const v4f*)(p0 + CP);          // x0+1
                const v4f v10 = *(const v4f*)p1;
                const v4f v11 = *(const v4f*)(p1 + CP);
#pragma unroll
                for (int cc = 0; cc < 4; ++cc)
                    res[cc][k] = fmaf(v11[cc], wgt[k][3], fmaf(v10[cc], wgt[k][2],
                                  fmaf(v01[cc], wgt[k][1], v00[cc] * wgt[k][0])));
            }
#pragma unroll
            for (int cc = 0; cc < 4; ++cc) {
                const v4f r = { res[cc][0], res[cc][1], res[cc][2], res[cc][3] };
                *(v4f*)(outw + (c0 + cc) * DHW + d * HW) = r;    // plain store (A/B vs nt)
            }
        }
    }

    // ---- left half: broadcast x rows over this block's 24 d (1-KB rows) ----
    {
        float* op0 = out + (cb + wave * 2 + 0) * DHW + dbase * HW + h * W + w0;
        float* op1 = out + (cb + wave * 2 + 1) * DHW + dbase * HW + h * W + w0;
        for (int d = 0; d < 24; ++d) {
            *(v4f*)(op0 + d * HW) = xv0;                         // plain store (A/B vs nt)
            *(v4f*)(op1 + d * HW) = xv1;
        }
    }
}

extern "C" void kernel_launch(void* const* d_in, const int* in_sizes, int n_in,
                              void* d_out, int out_size, void* d_ws, size_t ws_size,
                              hipStream_t stream) {
    const float* x    = (const float*)d_in[0];
    const float* y    = (const float*)d_in[1];
    const float* disp = (const float*)d_in[2];
    float* out = (float*)d_out;

    // (h=128) x (c-half=2) x (d-half=2) = 512 blocks, 512 threads, 51.8 KB LDS
    // -> 2 blocks/CU, 16 waves/CU
    cost_volume_kernel<<<dim3(512), dim3(512), 0, stream>>>(x, y, disp, out);
}